// Round 6
// baseline (2075.727 us; speedup 1.0000x reference)
//
#include <hip/hip_runtime.h>

#define BATCH 256
#define TT 512
#define CIN 512
#define UU 512
#define ZN 2048
#define BT (BATCH*TT)

typedef __attribute__((ext_vector_type(8))) short short8;
typedef __attribute__((ext_vector_type(4))) float f32x4;

__device__ __forceinline__ short f2bf(float f){
  unsigned u = __float_as_uint(f);
  u += 0x7fffu + ((u >> 16) & 1u);   // round-to-nearest-even
  return (short)(u >> 16);
}
__device__ __forceinline__ float bf2f(unsigned short s){
  unsigned u = ((unsigned)s) << 16;
  return __uint_as_float(u);
}

#define GLD16(g, l) __builtin_amdgcn_global_load_lds( \
    (const __attribute__((address_space(1))) void*)(g), \
    (__attribute__((address_space(3))) void*)(l), 16, 0, 0)

// coherent (device-scope, MALL) 16B load with immediate offset
#define CLOAD(dst, p, OFFSTR) asm volatile( \
    "global_load_dwordx4 %0, %1, off offset:" OFFSTR " sc0 sc1" \
    : "=v"(dst) : "v"(p) : "memory")
// coherent 4B load
#define CLOADW(dst, p) asm volatile( \
    "global_load_dword %0, %1, off sc0 sc1" \
    : "=v"(dst) : "v"(p) : "memory")

__device__ __forceinline__ void st_coh_u16(void* p, unsigned v){
  asm volatile("global_store_short %0, %1, off sc0 sc1" :: "v"(p), "v"(v) : "memory");
}
__device__ __forceinline__ void st_coh_u32(void* p, unsigned v){
  asm volatile("global_store_dword %0, %1, off sc0 sc1" :: "v"(p), "v"(v) : "memory");
}

__device__ __forceinline__ float sigm(float x){ return 1.0f/(1.0f + __expf(-x)); }
__device__ __forceinline__ float tanh_fast(float x){ return 1.0f - 2.0f/(1.0f + __expf(2.0f*x)); }

// ---------------- convert x [B][T][C] f32 -> x_tb [(t*B+b)][C] bf16 ----------------
__global__ __launch_bounds__(256) void convert_x_kernel(const float* __restrict__ x,
                                                        short* __restrict__ xb){
  const long total = (long)TT*BATCH*64;   // 8-elem chunks
  const long stride = (long)gridDim.x * blockDim.x;
  for (long i = (long)blockIdx.x * blockDim.x + threadIdx.x; i < total; i += stride){
    const int c8 = (int)(i & 63);
    const long tb = i >> 6;
    const int b = (int)(tb & (BATCH-1));
    const int t = (int)(tb >> 8);
    const float* src = x + ((long)b*TT + t)*CIN + c8*8;
    const float4 v0 = *(const float4*)(src);
    const float4 v1 = *(const float4*)(src + 4);
    short8 o;
    o[0]=f2bf(v0.x); o[1]=f2bf(v0.y); o[2]=f2bf(v0.z); o[3]=f2bf(v0.w);
    o[4]=f2bf(v1.x); o[5]=f2bf(v1.y); o[6]=f2bf(v1.z); o[7]=f2bf(v1.w);
    *(short8*)(xb + i*8) = o;
  }
}

// ---------------- transpose wx/wh: [512][2048] f32 -> [2048][512] bf16 ----------------
__global__ __launch_bounds__(256) void transpose_w_kernel(
    const float* __restrict__ wx, const float* __restrict__ wh,
    short* __restrict__ wxt, short* __restrict__ wht){
  const float* src = blockIdx.z ? wh : wx;
  short* dst = blockIdx.z ? wht : wxt;
  __shared__ float tile[32][33];
  const int nt = blockIdx.x << 5;
  const int kt = blockIdx.y << 5;
  const int tx = threadIdx.x & 31, ty = threadIdx.x >> 5;
  #pragma unroll
  for (int i = 0; i < 32; i += 8)
    tile[ty+i][tx] = src[(long)(kt+ty+i)*ZN + nt+tx];
  __syncthreads();
  #pragma unroll
  for (int i = 0; i < 32; i += 8)
    dst[(long)(nt+ty+i)*512 + kt+tx] = f2bf(tile[tx][ty+i]);
}

// ---------------- xpart GEMM with XCD panel swizzle ----------------
__global__ __launch_bounds__(256) void gemm_xpart_kernel(
    const short* __restrict__ A, const short* __restrict__ Bt,
    const float* __restrict__ bias, short* __restrict__ Co){
  __shared__ short As[128*32];
  __shared__ short Bs[128*32];
  const int wg = blockIdx.x;
  const int xcd = wg & 7;
  const int ii = wg >> 3;                       // 0..2047 per xcd
  const long m0 = (long)(xcd*128 + (ii >> 4)) << 7;
  const long n0 = (long)(ii & 15) << 7;
  const int tid = threadIdx.x;
  const int lane = tid & 63;
  const int wave = tid >> 6;
  const int wm = wave & 1, wn = wave >> 1;
  f32x4 acc[4][4] = {};
  const int srow = tid >> 2;
  const int sseg = tid & 3;
  const long aoff = (m0 + srow) * 512 + sseg * 8;
  const long boff = (n0 + srow) * 512 + sseg * 8;
  short* ldsa = &As[tid * 8];
  short* ldsb = &Bs[tid * 8];
  for (int k0 = 0; k0 < 512; k0 += 32){
    __syncthreads();
    GLD16(A + aoff + k0, ldsa);
    GLD16(A + aoff + 64*512 + k0, ldsa + 2048);
    GLD16(Bt + boff + k0, ldsb);
    GLD16(Bt + boff + 64*512 + k0, ldsb + 2048);
    __syncthreads();
    const int kb = (lane >> 4) * 8;
    short8 af[4], bf[4];
    #pragma unroll
    for (int mi = 0; mi < 4; mi++) af[mi] = *(const short8*)&As[(wm*64 + mi*16 + (lane&15))*32 + kb];
    #pragma unroll
    for (int ni = 0; ni < 4; ni++) bf[ni] = *(const short8*)&Bs[(wn*64 + ni*16 + (lane&15))*32 + kb];
    #pragma unroll
    for (int mi = 0; mi < 4; mi++)
      #pragma unroll
      for (int ni = 0; ni < 4; ni++)
        acc[mi][ni] = __builtin_amdgcn_mfma_f32_16x16x32_bf16(af[mi], bf[ni], acc[mi][ni], 0, 0, 0);
  }
  #pragma unroll
  for (int ni = 0; ni < 4; ni++){
    const long col = n0 + wn*64 + ni*16 + (lane & 15);
    const float bv = bias[col];
    #pragma unroll
    for (int mi = 0; mi < 4; mi++){
      const long row = m0 + wm*64 + mi*16 + ((lane >> 4) << 2);
      #pragma unroll
      for (int r = 0; r < 4; r++)
        Co[(row + r)*ZN + col] = f2bf(acc[mi][ni][r] + bv);
    }
  }
}

// ---------------- persistent LSTM recurrence (design E) ----------------
// 256 WGs x 256 thr, 1/CU: bg = blockIdx&15 (16 rows), cg = blockIdx>>4.
// 4 waves/WG = 2 ucol-groups x 2 K-halves. Each wave: 4 gate-tiles x 16
// ucols, K=256 register-resident wh (128 VGPR) -> each A-load feeds 4 MFMAs.
// h(t) staged once/WG into [k8][row] LDS (contiguous, conflict-free);
// A-read = base + m*1024 + lane*16 (canonical contiguous). K-half partials
// exchanged pairwise via contiguous LDS; gates lane-local; each lane owns
// 2 (row,ucol) cells (c in regs). Barrier protocol as R5 (validated).
__global__ __launch_bounds__(256, 1) void lstm_persist_kernel(
    const short* __restrict__ xpart, const float* __restrict__ dones,
    const short* __restrict__ wht, short* __restrict__ hb0,
    short* __restrict__ hb1, unsigned* __restrict__ flags,
    float* __restrict__ out){
  __shared__ short h_lds[8192];      // [k8=64][row=16][8] = 16KB
  __shared__ float zx[4096];         // [wv=4][g=4][lane=64][r=4] = 16KB
  const int tid = threadIdx.x;
  const int l = tid & 63;
  const int wv = tid >> 6;           // 0..3
  const int kh = wv & 1;             // K-half
  const int ug = wv >> 1;            // 16-ucol group within WG
  const int bg = blockIdx.x & 15;
  const int cg = blockIdx.x >> 4;    // 0..15
  const int rb = bg << 4;
  const int ucw = (cg << 5) + (ug << 4);
  const int j = l & 15;
  const int hq = l >> 4;

  // ---- loop-invariant B fragments: 4 gates x 8 k-chunks of K-half kh ----
  short8 bfr[4][8];
  #pragma unroll
  for (int g = 0; g < 4; g++){
    const short* wsrc = wht + ((long)(g*512 + ucw + j))*512 + kh*256 + hq*8;
    #pragma unroll
    for (int m = 0; m < 8; m++)
      bfr[g][m] = *(const short8*)(wsrc + m*32);
  }

  // ---- staging mapping: thread -> (row, 4 k8-chunks) ----
  const int srow = tid & 15;
  const int skg  = tid >> 4;                        // 0..15
  const long sgoff = (long)(rb + srow)*UU + skg*32; // u16 index into h buf
  short* sdst = h_lds + skg*512 + srow*8;           // u16 index

  // ---- cell mapping: lane owns rows (hq*4 + kh*2 + {0,1}), ucol ucw+j ----
  const int row0 = rb + hq*4 + kh*2;
  const int ucol = ucw + j;

  unsigned* fl = flags + bg*16;
  const unsigned short* xp16 = (const unsigned short*)xpart;

  float c0 = 0.f, c1 = 0.f;
  float dn0, dn1;
  unsigned short xp0[4], xp1[4];
  dn0 = dones[(long)row0*TT];
  dn1 = dones[(long)(row0+1)*TT];
  #pragma unroll
  for (int g = 0; g < 4; g++){
    xp0[g] = xp16[(long)row0*ZN + (g<<9) + ucol];
    xp1[g] = xp16[(long)(row0+1)*ZN + (g<<9) + ucol];
  }

  for (int t = 0; t < TT; t++){
    // ---- stage h(t) -> LDS [k8][row] (coherent; transpose via addressing) ----
    {
      const short* hs = ((t & 1) ? hb1 : hb0) + sgoff;
      short8 v0, v1, v2, v3;
      CLOAD(v0, hs, "0"); CLOAD(v1, hs, "16"); CLOAD(v2, hs, "32"); CLOAD(v3, hs, "48");
      asm volatile("s_waitcnt vmcnt(0)" ::: "memory");
      *(short8*)(sdst      ) = v0;
      *(short8*)(sdst + 128) = v1;
      *(short8*)(sdst + 256) = v2;
      *(short8*)(sdst + 384) = v3;
    }
    __syncthreads();
    // ---- A-frags (contiguous LDS) + MFMA: each a feeds 4 gate-tiles ----
    f32x4 acc[4] = {};
    const short* abase = h_lds + kh*4096 + l*8;   // u16 idx
    #pragma unroll
    for (int m = 0; m < 8; m++){
      const short8 a = *(const short8*)(abase + m*512);
      #pragma unroll
      for (int g = 0; g < 4; g++)
        acc[g] = __builtin_amdgcn_mfma_f32_16x16x32_bf16(a, bfr[g][m], acc[g], 0, 0, 0);
    }
    // ---- pairwise K-half exchange (contiguous LDS) ----
    #pragma unroll
    for (int g = 0; g < 4; g++)
      *(f32x4*)&zx[(wv*4 + g)*256 + l*4] = acc[g];
    __syncthreads();
    const int pvb = (wv ^ 1)*4;
    f32x4 pz[4];
    #pragma unroll
    for (int g = 0; g < 4; g++)
      pz[g] = *(const f32x4*)&zx[(pvb + g)*256 + l*4];
    // ---- full z for this wave's r-cells (compile-time vec indices) ----
    float zs0[4], zs1[4];
    #pragma unroll
    for (int g = 0; g < 4; g++){
      zs0[g] = kh ? (acc[g][2] + pz[g][2]) : (acc[g][0] + pz[g][0]);
      zs1[g] = kh ? (acc[g][3] + pz[g][3]) : (acc[g][1] + pz[g][1]);
    }
    // ---- gates / state update (lane-local) ----
    const float keep0 = 1.0f - dn0;
    const float keep1 = 1.0f - dn1;
    const float z00 = bf2f(xp0[0]) + keep0*zs0[0];
    const float z01 = bf2f(xp0[1]) + keep0*zs0[1];
    const float z02 = bf2f(xp0[2]) + keep0*zs0[2];
    const float z03 = bf2f(xp0[3]) + keep0*zs0[3];
    const float z10 = bf2f(xp1[0]) + keep1*zs1[0];
    const float z11 = bf2f(xp1[1]) + keep1*zs1[1];
    const float z12 = bf2f(xp1[2]) + keep1*zs1[2];
    const float z13 = bf2f(xp1[3]) + keep1*zs1[3];
    const float gi0 = sigm(z00), gf0 = sigm(z01), go0 = sigm(z02), gu0 = tanh_fast(z03);
    const float gi1 = sigm(z10), gf1 = sigm(z11), go1 = sigm(z12), gu1 = tanh_fast(z13);
    const float cn0 = gf0*(c0*keep0) + gi0*gu0;
    const float cn1 = gf1*(c1*keep1) + gi1*gu1;
    const float hn0 = go0 * tanh_fast(cn0);
    const float hn1 = go1 * tanh_fast(cn1);
    c0 = cn0; c1 = cn1;
    const long ob0 = (long)row0*TT*UU + (long)t*UU + ucol;
    if (t == TT-1){
      out[ob0] = hn0;
      out[ob0 + (long)TT*UU] = hn1;
      float* s = out + (long)BATCH*TT*UU;
      s[(long)row0*2*UU + ucol] = cn0;
      s[(long)row0*2*UU + UU + ucol] = hn0;
      s[(long)(row0+1)*2*UU + ucol] = cn1;
      s[(long)(row0+1)*2*UU + UU + ucol] = hn1;
    } else {
      // release: h(t+1) store -> drain -> WG sync -> flag
      short* hdst = (t & 1) ? hb0 : hb1;
      st_coh_u16(hdst + (long)row0*UU + ucol, (unsigned)(unsigned short)f2bf(hn0));
      st_coh_u16(hdst + (long)(row0+1)*UU + ucol, (unsigned)(unsigned short)f2bf(hn1));
      asm volatile("s_waitcnt vmcnt(0)" ::: "memory");
      __syncthreads();
      if (tid == 0) st_coh_u32(fl + cg, (unsigned)(t+1));
      // overlap with poll: out-stores + next-step prefetch (cached paths)
      out[ob0] = hn0;
      out[ob0 + (long)TT*UU] = hn1;
      dn0 = dones[(long)row0*TT + (t+1)];
      dn1 = dones[(long)(row0+1)*TT + (t+1)];
      const long xb = ((long)(t+1)*BATCH)*ZN + ucol;
      #pragma unroll
      for (int g = 0; g < 4; g++){
        xp0[g] = xp16[xb + (long)row0*ZN + (g<<9)];
        xp1[g] = xp16[xb + (long)(row0+1)*ZN + (g<<9)];
      }
      // single-wave poll of the bg's 16 flags, with backoff
      if (wv == 0){
        const unsigned tgt = (unsigned)(t+1);
        unsigned v;
        for (;;){
          CLOADW(v, fl + (l & 15));
          asm volatile("s_waitcnt vmcnt(0)" ::: "memory");
          if (__all((int)(v >= tgt))) break;
          __builtin_amdgcn_s_sleep(1);
        }
      }
      __syncthreads();
    }
  }
}

extern "C" void kernel_launch(void* const* d_in, const int* in_sizes, int n_in,
                              void* d_out, int out_size, void* d_ws, size_t ws_size,
                              hipStream_t stream){
  const float* x     = (const float*)d_in[0];
  const float* dones = (const float*)d_in[1];
  const float* wx    = (const float*)d_in[2];
  const float* wh    = (const float*)d_in[3];
  const float* b     = (const float*)d_in[4];
  float* out = (float*)d_out;
  char* ws = (char*)d_ws;
  short* x_tb  = (short*)(ws);                    // 134,217,728 B
  short* wx_t  = (short*)(ws + 134217728L);       //   2,097,152 B
  short* wh_t  = (short*)(ws + 136314880L);       //   2,097,152 B
  short* xpart = (short*)(ws + 138412032L);       // 536,870,912 B
  short* hb0   = (short*)(ws + 675282944L);       //     262,144 B
  short* hb1   = (short*)(ws + 675545088L);       //     262,144 B
  unsigned* flags = (unsigned*)(ws + 675807232L); //       1,024 B

  hipMemsetAsync(hb0, 0, 262144, stream);
  hipMemsetAsync(flags, 0, 1024, stream);
  convert_x_kernel<<<2048, 256, 0, stream>>>(x, x_tb);
  transpose_w_kernel<<<dim3(64,16,2), 256, 0, stream>>>(wx, wh, wx_t, wh_t);
  gemm_xpart_kernel<<<16384, 256, 0, stream>>>(x_tb, wx_t, b, xpart);
  lstm_persist_kernel<<<256, 256, 0, stream>>>(xpart, dones, wh_t, hb0, hb1, flags, out);
}